// Round 1
// baseline (29.654 us; speedup 1.0000x reference)
//
#include <hip/hip_runtime.h>

// 7x7 stride-2 VALID cross-correlation on 4096x4096 fp32, single channel.
// out[i,j] = sum_{p,q} X[2i+p, 2j+q] * W[p,q], out is 2045x2045.

static constexpr int H    = 4096;
static constexpr int OUT  = 2045;   // (4096 - 7)/2 + 1

// Block tile: 32 output rows x 64 output cols; 256 threads (16x16);
// each thread computes a 2x4 output micro-tile.
__global__ __launch_bounds__(256) void conv7s2_kernel(
    const float* __restrict__ X,
    const float* __restrict__ W,
    float* __restrict__ out)
{
    const int tx = threadIdx.x & 15;   // 16 threads across cols
    const int ty = threadIdx.x >> 4;   // 16 threads across rows
    const int x0 = blockIdx.x * 64 + tx * 4;   // first output col of this thread
    const int y0 = blockIdx.y * 32 + ty * 2;   // first output row of this thread

    // W is tiny and uniform across the wave -> compiler scalarizes to s_load;
    // FMAs then use the SGPR as the weight operand.
    float w[49];
#pragma unroll
    for (int i = 0; i < 49; ++i) w[i] = W[i];

    float acc0[4] = {0.f, 0.f, 0.f, 0.f};   // output row y0
    float acc1[4] = {0.f, 0.f, 0.f, 0.f};   // output row y0+1

    const int cbase = x0 * 2;   // input col base; thread needs cols cbase..cbase+12
    const int rbase = y0 * 2;   // input row base; thread needs rows rbase..rbase+8

    // Four float4 loads per row cover cols cbase..cbase+15 (16B aligned:
    // cbase is a multiple of 8 floats). Clamp any fully-out-of-range float4
    // to a safe in-bounds address; the garbage only ever feeds outputs that
    // fail the store guard (any float4 containing a column needed by a VALID
    // output is provably fully in-bounds).
    int c[4];
#pragma unroll
    for (int k = 0; k < 4; ++k) {
        int ck = cbase + 4 * k;
        c[k] = (ck + 4 <= H) ? ck : (H - 4);
    }

#pragma unroll
    for (int r = 0; r < 9; ++r) {
        int row = rbase + r;
        if (row >= H) row = H - 1;   // garbage rows only feed invalid outputs
        const float* rp = X + (size_t)row * H;

        float rv[16];
#pragma unroll
        for (int k = 0; k < 4; ++k) {
            const float4 v = *reinterpret_cast<const float4*>(rp + c[k]);
            rv[4 * k + 0] = v.x;
            rv[4 * k + 1] = v.y;
            rv[4 * k + 2] = v.z;
            rv[4 * k + 3] = v.w;
        }

        // Row r of the 9-row span contributes with kernel row p=r to the
        // first output row (r in [0,6]) and p=r-2 to the second (r in [2,8]).
#pragma unroll
        for (int q = 0; q < 7; ++q) {
#pragma unroll
            for (int j = 0; j < 4; ++j) {
                const float cv = rv[2 * j + q];
                if (r <= 6) acc0[j] = fmaf(cv, w[r * 7 + q],       acc0[j]);
                if (r >= 2) acc1[j] = fmaf(cv, w[(r - 2) * 7 + q], acc1[j]);
            }
        }
    }

#pragma unroll
    for (int j = 0; j < 4; ++j) {
        const int x = x0 + j;
        if (x < OUT) {
            if (y0     < OUT) out[(size_t)y0       * OUT + x] = acc0[j];
            if (y0 + 1 < OUT) out[(size_t)(y0 + 1) * OUT + x] = acc1[j];
        }
    }
}

extern "C" void kernel_launch(void* const* d_in, const int* in_sizes, int n_in,
                              void* d_out, int out_size, void* d_ws, size_t ws_size,
                              hipStream_t stream) {
    const float* X = (const float*)d_in[0];
    const float* W = (const float*)d_in[1];
    float* out = (float*)d_out;

    // grid: ceil(2045/64)=32 tiles in x, ceil(2045/32)=64 tiles in y
    dim3 grid(32, 64);
    conv7s2_kernel<<<grid, 256, 0, stream>>>(X, W, out);
}

// Round 2
// 28.968 us; speedup vs baseline: 1.0237x; 1.0237x over previous
//
#include <hip/hip_runtime.h>

// 7x7 stride-2 VALID cross-correlation on 4096x4096 fp32, single channel.
// out[i,j] = sum_{p,q} X[2i+p, 2j+q] * W[p,q], out is 2045x2045.
//
// Block tile: 64x64 outputs, 256 threads (16x16), each thread a 4x4 micro-tile.
// Per thread: 13 input rows x 16 cols (4x float4), vertical reuse in-register
// (each input row feeds up to 4 accumulator rows).

static constexpr int H   = 4096;
static constexpr int OUT = 2045;   // (4096 - 7)/2 + 1

__global__ __launch_bounds__(256) void conv7s2_kernel(
    const float* __restrict__ X,
    const float* __restrict__ W,
    float* __restrict__ out)
{
    const int tx = threadIdx.x & 15;
    const int ty = threadIdx.x >> 4;
    const int x0 = blockIdx.x * 64 + tx * 4;   // first output col
    const int y0 = blockIdx.y * 64 + ty * 4;   // first output row

    // Uniform-address loads -> compiler scalarizes to s_load; FMAs take the
    // weight as the SGPR operand.
    float w[49];
#pragma unroll
    for (int i = 0; i < 49; ++i) w[i] = W[i];

    float acc[4][4];
#pragma unroll
    for (int oi = 0; oi < 4; ++oi)
#pragma unroll
        for (int j = 0; j < 4; ++j) acc[oi][j] = 0.f;

    const int cbase = x0 * 2;   // needs input cols cbase..cbase+12
    const int rbase = y0 * 2;   // needs input rows rbase..rbase+12

    // 16B-aligned float4 loads (cbase is a multiple of 8 floats). Clamp
    // out-of-range addresses; garbage only feeds outputs behind store guards.
    int c[4];
#pragma unroll
    for (int k = 0; k < 4; ++k) {
        int ck = cbase + 4 * k;
        c[k] = (ck + 4 <= H) ? ck : (H - 4);
    }

#pragma unroll
    for (int r = 0; r < 13; ++r) {
        int row = rbase + r;
        if (row >= H) row = H - 1;   // garbage rows only feed invalid outputs
        const float* rp = X + (size_t)row * H;

        float rv[16];
#pragma unroll
        for (int k = 0; k < 4; ++k) {
            const float4 v = *reinterpret_cast<const float4*>(rp + c[k]);
            rv[4 * k + 0] = v.x;
            rv[4 * k + 1] = v.y;
            rv[4 * k + 2] = v.z;
            rv[4 * k + 3] = v.w;
        }

        // Input row r contributes with kernel row p = r - 2*oi to output row oi.
#pragma unroll
        for (int oi = 0; oi < 4; ++oi) {
            const int p = r - 2 * oi;
            if (p >= 0 && p <= 6) {
#pragma unroll
                for (int q = 0; q < 7; ++q) {
#pragma unroll
                    for (int j = 0; j < 4; ++j) {
                        acc[oi][j] = fmaf(rv[2 * j + q], w[p * 7 + q], acc[oi][j]);
                    }
                }
            }
        }
    }

#pragma unroll
    for (int oi = 0; oi < 4; ++oi) {
        const int y = y0 + oi;
        if (y < OUT) {
#pragma unroll
            for (int j = 0; j < 4; ++j) {
                const int x = x0 + j;
                if (x < OUT) out[(size_t)y * OUT + x] = acc[oi][j];
            }
        }
    }
}

extern "C" void kernel_launch(void* const* d_in, const int* in_sizes, int n_in,
                              void* d_out, int out_size, void* d_ws, size_t ws_size,
                              hipStream_t stream) {
    const float* X = (const float*)d_in[0];
    const float* W = (const float*)d_in[1];
    float* out = (float*)d_out;

    // ceil(2045/64) = 32 tiles each way
    dim3 grid(32, 32);
    conv7s2_kernel<<<grid, 256, 0, stream>>>(X, W, out);
}